// Round 2
// baseline (648.657 us; speedup 1.0000x reference)
//
#include <hip/hip_runtime.h>
#include <hip/hip_bf16.h>

#define NND 8192
#define NHEADS 4
#define HD 64

typedef __attribute__((ext_vector_type(8))) __bf16 bf16x8;
typedef __attribute__((ext_vector_type(4))) float f32x4;
typedef __attribute__((ext_vector_type(4))) unsigned int u32x4;
typedef __attribute__((ext_vector_type(4))) int i32x4;

// Phase 1: Wh[h][n][d] = sum_i h[n][i] W[h][i][d]; s1 = Wh.a1, s2 = Wh.a2;
// store WhT as bf16 [head][d][n]  (so phase-2 B-fragments are 8 contiguous j's).
__global__ __launch_bounds__(256) void gat_phase1(
    const float* __restrict__ hin, const float* __restrict__ W, const float* __restrict__ av,
    float* __restrict__ s1, float* __restrict__ s2, unsigned short* __restrict__ whbT)
{
  __shared__ __align__(16) float hl[32][256];
  const int t = threadIdx.x;
  const int n0 = blockIdx.x * 32;
  // stage 32x256 h tile (coalesced float4)
  #pragma unroll
  for (int k = 0; k < 8; ++k) {
    int off = k * 1024 + t * 4;
    int r = off >> 8, c = off & 255;
    *(f32x4*)&hl[r][c] = *(const f32x4*)&hin[(size_t)(n0 + r) * 256 + c];
  }
  __syncthreads();
  const int head = t >> 6;           // wave == head
  const int d = t & 63;
  const int lane = t & 63;
  const float* Wc = W + head * 256 * 64 + d;   // W[head][i][d], i-stride 64 floats
  float acc[32];
  #pragma unroll
  for (int n = 0; n < 32; ++n) acc[n] = 0.f;
  for (int i0 = 0; i0 < 256; i0 += 4) {
    float w0 = Wc[(i0 + 0) * 64];
    float w1 = Wc[(i0 + 1) * 64];
    float w2 = Wc[(i0 + 2) * 64];
    float w3 = Wc[(i0 + 3) * 64];
    #pragma unroll
    for (int n = 0; n < 32; ++n) {
      f32x4 hv = *(const f32x4*)&hl[n][i0];   // lane-uniform address -> LDS broadcast
      float a0 = __builtin_fmaf(hv[0], w0, acc[n]);
      float a1 = __builtin_fmaf(hv[1], w1, a0);
      float a2 = __builtin_fmaf(hv[2], w2, a1);
      acc[n]   = __builtin_fmaf(hv[3], w3, a2);
    }
  }
  const float a1v = av[d];        // a[:64]
  const float a2v = av[64 + d];   // a[64:]
  #pragma unroll
  for (int n = 0; n < 32; ++n) {
    float v1 = acc[n] * a1v;
    float v2 = acc[n] * a2v;
    #pragma unroll
    for (int off = 32; off; off >>= 1) {
      v1 += __shfl_xor(v1, off, 64);
      v2 += __shfl_xor(v2, off, 64);
    }
    if (lane == 0) {
      s1[head * NND + n0 + n] = v1;
      s2[head * NND + n0 + n] = v2;
    }
  }
  // store transposed bf16: whbT[(head*64+d)*NND + n] ; row index == t
  #pragma unroll
  for (int k = 0; k < 4; ++k) {
    union { unsigned short us[8]; u32x4 v; } u;
    #pragma unroll
    for (int e = 0; e < 8; ++e)
      u.us[e] = __builtin_bit_cast(unsigned short, (__bf16)acc[k * 8 + e]);
    *(u32x4*)&whbT[(size_t)t * NND + n0 + k * 8] = u.v;
  }
}

// Phase 2: fused masked-exp attention + PV via MFMA.
// Block: 32 rows (i), all 4 heads. 8 waves: wave=(head, rhalf). Single pass over j,
// accumulating numerator (MFMA, bf16) and denominator (f32) simultaneously.
__global__ __launch_bounds__(512) void gat_phase2(
    const int* __restrict__ adj, const float* __restrict__ s1, const float* __restrict__ s2,
    const unsigned short* __restrict__ whbT, float* __restrict__ out)
{
  __shared__ __align__(16) int adjT[32 * 68];   // 32 rows, stride 68 dwords (2-way-conflict free)
  const int t = threadIdx.x;
  const int wave = t >> 6, lane = t & 63;
  const int head = wave & 3, rhalf = wave >> 2;
  const int i0 = blockIdx.x * 32;
  const int lo = lane & 15, kg = lane >> 4;
  const int rowA = rhalf * 16 + lo;             // A-fragment row within 32-row block
  const float s1v = s1[head * NND + i0 + rowA];
  const float* s2h = s2 + head * NND;
  const unsigned short* wb = whbT + (size_t)(head * 64 + lo) * NND;
  f32x4 acc[4];
  #pragma unroll
  for (int dt = 0; dt < 4; ++dt) acc[dt] = (f32x4)(0.f);
  float denom = 0.f;
  const int stR = t >> 4, stC = (t & 15) * 4;   // staging: one int4 per thread
  const int* adjP = adj + (size_t)(i0 + stR) * NND + stC;

  for (int jt = 0; jt < 128; ++jt) {
    const int j0 = jt * 64;
    // prefetch (independent of LDS) before barriers
    i32x4 st = *(const i32x4*)(adjP + j0);
    bf16x8 bfr[8];
    #pragma unroll
    for (int ks = 0; ks < 2; ++ks) {
      #pragma unroll
      for (int dt = 0; dt < 4; ++dt) {
        bfr[ks * 4 + dt] = __builtin_bit_cast(bf16x8,
            *(const u32x4*)(wb + (size_t)dt * 16 * NND + j0 + ks * 32 + kg * 8));
      }
    }
    f32x4 sA = *(const f32x4*)&s2h[j0 + kg * 8];
    f32x4 sB = *(const f32x4*)&s2h[j0 + kg * 8 + 4];
    f32x4 sC = *(const f32x4*)&s2h[j0 + 32 + kg * 8];
    f32x4 sD = *(const f32x4*)&s2h[j0 + 32 + kg * 8 + 4];
    __syncthreads();                       // previous tile's compute done
    *(i32x4*)&adjT[stR * 68 + stC] = st;
    __syncthreads();                       // staging visible
    #pragma unroll
    for (int ks = 0; ks < 2; ++ks) {
      const int jb = ks * 32 + kg * 8;
      i32x4 m0 = *(const i32x4*)&adjT[rowA * 68 + jb];
      i32x4 m1 = *(const i32x4*)&adjT[rowA * 68 + jb + 4];
      f32x4 sx = ks ? sC : sA;
      f32x4 sy = ks ? sD : sB;
      bf16x8 af;
      float ds = 0.f;
      #pragma unroll
      for (int e = 0; e < 4; ++e) {
        float x = s1v + sx[e];
        x = fmaxf(x, 0.2f * x);            // leaky relu
        x = (m0[e] != 0) ? x : -1e30f;     // mask -> exp gives exactly 0
        float w = __expf(x);
        __bf16 wv = (__bf16)w;
        af[e] = wv;
        ds += (float)wv;                   // denom from the *rounded* weights
      }
      #pragma unroll
      for (int e = 0; e < 4; ++e) {
        float x = s1v + sy[e];
        x = fmaxf(x, 0.2f * x);
        x = (m1[e] != 0) ? x : -1e30f;
        float w = __expf(x);
        __bf16 wv = (__bf16)w;
        af[4 + e] = wv;
        ds += (float)wv;
      }
      denom += ds;
      #pragma unroll
      for (int dt = 0; dt < 4; ++dt)
        acc[dt] = __builtin_amdgcn_mfma_f32_16x16x32_bf16(af, bfr[ks * 4 + dt], acc[dt], 0, 0, 0);
    }
  }
  // full row-denominator: reduce over the 4 k-groups (lanes sharing lane&15)
  denom += __shfl_xor(denom, 16, 64);
  denom += __shfl_xor(denom, 32, 64);
  float rrec[4];
  #pragma unroll
  for (int r = 0; r < 4; ++r) {
    float dr = __shfl(denom, kg * 4 + r, 64);  // lane (kg*4+r) holds denom of C-row kg*4+r
    rrec[r] = 1.0f / dr;
  }
  // C layout: col = lane&15, row = kg*4 + r  (HW-verified)
  float* op = out + (size_t)(i0 + rhalf * 16 + kg * 4) * 256 + head * 64 + lo;
  #pragma unroll
  for (int dt = 0; dt < 4; ++dt) {
    #pragma unroll
    for (int r = 0; r < 4; ++r)
      op[r * 256 + dt * 16] = acc[dt][r] * rrec[r];
  }
}

extern "C" void kernel_launch(void* const* d_in, const int* in_sizes, int n_in,
                              void* d_out, int out_size, void* d_ws, size_t ws_size,
                              hipStream_t stream) {
  const float* h   = (const float*)d_in[0];
  const int*   adj = (const int*)d_in[1];
  const float* W   = (const float*)d_in[2];
  const float* a   = (const float*)d_in[3];
  float* out = (float*)d_out;
  float* s1 = (float*)d_ws;                         // 4*8192 f32
  float* s2 = s1 + NHEADS * NND;                    // 4*8192 f32
  unsigned short* whbT = (unsigned short*)(s2 + NHEADS * NND);  // 4*64*8192 bf16 = 4MB
  gat_phase1<<<dim3(NND / 32), dim3(256), 0, stream>>>(h, W, a, s1, s2, whbT);
  gat_phase2<<<dim3(NND / 32), dim3(512), 0, stream>>>(adj, s1, s2, whbT, out);
}

// Round 3
// 567.977 us; speedup vs baseline: 1.1420x; 1.1420x over previous
//
#include <hip/hip_runtime.h>
#include <hip/hip_bf16.h>

#define NND 8192

typedef __attribute__((ext_vector_type(8))) __bf16 bf16x8;
typedef __attribute__((ext_vector_type(4))) float f32x4;
typedef __attribute__((ext_vector_type(4))) unsigned int u32x4;
typedef __attribute__((ext_vector_type(4))) int i32x4;

// ---------------- Phase 1: WhT(bf16) + s1/s2 via MFMA ----------------
// Computes WhT[hd][n] = sum_i W[h][i][d] * h[n][i]  (M=hd, N=n, K=i).
// A-frag = W^T (row=hd, k=i, stride-64 scalar loads, L2-resident, tiny),
// B-frag = h^T (k=i contiguous in h's rows -> straight f32x4 global loads).
// s1/s2 from the f32 accumulator in-epilogue (d-reduction across lanes).
__global__ __launch_bounds__(256) void gat_phase1(
    const float* __restrict__ hin, const float* __restrict__ W, const float* __restrict__ av,
    float* __restrict__ s1, float* __restrict__ s2, unsigned short* __restrict__ whbT)
{
  const int t = threadIdx.x;
  const int head = t >> 6, lane = t & 63;
  const int lo = lane & 15, kg = lane >> 4;
  const int n0 = blockIdx.x * 16;
  const float* hrow = hin + (size_t)(n0 + lo) * 256;
  const float* Wp = W + head * 16384;          // W[head][i][d]
  f32x4 acc[4];
  #pragma unroll
  for (int rt = 0; rt < 4; ++rt) acc[rt] = (f32x4)(0.f);

  #pragma unroll 2
  for (int ks = 0; ks < 8; ++ks) {
    const int kb = ks * 32 + kg * 8;           // k = kb + e, e=0..7
    f32x4 h0 = *(const f32x4*)(hrow + kb);
    f32x4 h1 = *(const f32x4*)(hrow + kb + 4);
    bf16x8 bf;
    #pragma unroll
    for (int e = 0; e < 4; ++e) { bf[e] = (__bf16)h0[e]; bf[e + 4] = (__bf16)h1[e]; }
    #pragma unroll
    for (int rt = 0; rt < 4; ++rt) {
      bf16x8 af;
      #pragma unroll
      for (int e = 0; e < 8; ++e)
        af[e] = (__bf16)Wp[(kb + e) * 64 + rt * 16 + lo];   // W[h][k][d], d=rt*16+lo
      acc[rt] = __builtin_amdgcn_mfma_f32_16x16x32_bf16(af, bf, acc[rt], 0, 0, 0);
    }
  }
  // C layout: col(lane&15)=n, row(kg*4+r)=hd-within-tile
  #pragma unroll
  for (int rt = 0; rt < 4; ++rt) {
    #pragma unroll
    for (int r = 0; r < 4; ++r) {
      int hd = head * 64 + rt * 16 + kg * 4 + r;
      whbT[(size_t)hd * NND + n0 + lo] =
          __builtin_bit_cast(unsigned short, (__bf16)acc[rt][r]);
    }
  }
  float p1 = 0.f, p2 = 0.f;
  #pragma unroll
  for (int rt = 0; rt < 4; ++rt) {
    #pragma unroll
    for (int r = 0; r < 4; ++r) {
      int d = rt * 16 + kg * 4 + r;
      p1 = __builtin_fmaf(acc[rt][r], av[d], p1);
      p2 = __builtin_fmaf(acc[rt][r], av[64 + d], p2);
    }
  }
  p1 += __shfl_xor(p1, 16, 64); p1 += __shfl_xor(p1, 32, 64);
  p2 += __shfl_xor(p2, 16, 64); p2 += __shfl_xor(p2, 32, 64);
  if (kg == 0) {
    s1[head * NND + n0 + lo] = p1;
    s2[head * NND + n0 + lo] = p2;
  }
}

// ---------------- Phase 2: fused masked-exp attention + PV ----------------
// 1024 threads = 16 waves = 4 heads x 4 j-segments; 32 rows per block;
// grid 256. Barrier-free main loop; cross-jseg reduce via LDS at the end.
__global__ __launch_bounds__(1024, 4) void gat_phase2(
    const int* __restrict__ adj, const float* __restrict__ s1, const float* __restrict__ s2,
    const unsigned short* __restrict__ whbT, float* __restrict__ out)
{
  __shared__ float red[4][64][36];   // 36 KB, epilogue-only
  const int t = threadIdx.x;
  const int wave = t >> 6, lane = t & 63;
  const int head = wave & 3, jseg = wave >> 2;
  const int i0 = blockIdx.x * 32;
  const int lo = lane & 15, kg = lane >> 4;
  const float s1v0 = s1[head * NND + i0 + lo];
  const float s1v1 = s1[head * NND + i0 + 16 + lo];
  const float* s2h = s2 + head * NND;
  const unsigned short* wb0 = whbT + (size_t)(head * 64 + lo) * NND;
  const unsigned short* wb1 = wb0 + (size_t)16 * NND;
  const unsigned short* wb2 = wb0 + (size_t)32 * NND;
  const unsigned short* wb3 = wb0 + (size_t)48 * NND;
  const int* adjR0 = adj + (size_t)(i0 + lo) * NND;
  const int* adjR1 = adj + (size_t)(i0 + 16 + lo) * NND;
  f32x4 acc0[4], acc1[4];
  #pragma unroll
  for (int dt = 0; dt < 4; ++dt) { acc0[dt] = (f32x4)(0.f); acc1[dt] = (f32x4)(0.f); }
  float den0 = 0.f, den1 = 0.f;
  const int jbase = jseg * 2048;

  for (int jt = 0; jt < 32; ++jt) {
    const int j0 = jbase + jt * 64;
    #pragma unroll
    for (int ks = 0; ks < 2; ++ks) {
      const int jb = j0 + ks * 32 + kg * 8;
      u32x4 b0 = *(const u32x4*)(wb0 + jb);
      u32x4 b1 = *(const u32x4*)(wb1 + jb);
      u32x4 b2 = *(const u32x4*)(wb2 + jb);
      u32x4 b3 = *(const u32x4*)(wb3 + jb);
      i32x4 m0a = *(const i32x4*)(adjR0 + jb);
      i32x4 m0b = *(const i32x4*)(adjR0 + jb + 4);
      i32x4 m1a = *(const i32x4*)(adjR1 + jb);
      i32x4 m1b = *(const i32x4*)(adjR1 + jb + 4);
      f32x4 sa = *(const f32x4*)(s2h + jb);
      f32x4 sb = *(const f32x4*)(s2h + jb + 4);
      // row-group 0
      {
        bf16x8 af;
        #pragma unroll
        for (int e = 0; e < 4; ++e) {
          float x = s1v0 + sa[e];
          x = fmaxf(x, 0.2f * x);
          float w = (m0a[e] != 0) ? __expf(x) : 0.0f;   // exp independent of mask load
          af[e] = (__bf16)w;
          den0 += (float)af[e];
        }
        #pragma unroll
        for (int e = 0; e < 4; ++e) {
          float x = s1v0 + sb[e];
          x = fmaxf(x, 0.2f * x);
          float w = (m0b[e] != 0) ? __expf(x) : 0.0f;
          af[e + 4] = (__bf16)w;
          den0 += (float)af[e + 4];
        }
        acc0[0] = __builtin_amdgcn_mfma_f32_16x16x32_bf16(af, __builtin_bit_cast(bf16x8, b0), acc0[0], 0, 0, 0);
        acc0[1] = __builtin_amdgcn_mfma_f32_16x16x32_bf16(af, __builtin_bit_cast(bf16x8, b1), acc0[1], 0, 0, 0);
        acc0[2] = __builtin_amdgcn_mfma_f32_16x16x32_bf16(af, __builtin_bit_cast(bf16x8, b2), acc0[2], 0, 0, 0);
        acc0[3] = __builtin_amdgcn_mfma_f32_16x16x32_bf16(af, __builtin_bit_cast(bf16x8, b3), acc0[3], 0, 0, 0);
      }
      // row-group 1
      {
        bf16x8 af;
        #pragma unroll
        for (int e = 0; e < 4; ++e) {
          float x = s1v1 + sa[e];
          x = fmaxf(x, 0.2f * x);
          float w = (m1a[e] != 0) ? __expf(x) : 0.0f;
          af[e] = (__bf16)w;
          den1 += (float)af[e];
        }
        #pragma unroll
        for (int e = 0; e < 4; ++e) {
          float x = s1v1 + sb[e];
          x = fmaxf(x, 0.2f * x);
          float w = (m1b[e] != 0) ? __expf(x) : 0.0f;
          af[e + 4] = (__bf16)w;
          den1 += (float)af[e + 4];
        }
        acc1[0] = __builtin_amdgcn_mfma_f32_16x16x32_bf16(af, __builtin_bit_cast(bf16x8, b0), acc1[0], 0, 0, 0);
        acc1[1] = __builtin_amdgcn_mfma_f32_16x16x32_bf16(af, __builtin_bit_cast(bf16x8, b1), acc1[1], 0, 0, 0);
        acc1[2] = __builtin_amdgcn_mfma_f32_16x16x32_bf16(af, __builtin_bit_cast(bf16x8, b2), acc1[2], 0, 0, 0);
        acc1[3] = __builtin_amdgcn_mfma_f32_16x16x32_bf16(af, __builtin_bit_cast(bf16x8, b3), acc1[3], 0, 0, 0);
      }
    }
  }
  // per-row denominators (reduce across kg groups)
  den0 += __shfl_xor(den0, 16, 64); den0 += __shfl_xor(den0, 32, 64);
  den1 += __shfl_xor(den1, 16, 64); den1 += __shfl_xor(den1, 32, 64);

  // cross-jseg reduction (3 rounds, LDS slot per head)
  for (int s = 1; s <= 3; ++s) {
    if (jseg == s) {
      #pragma unroll
      for (int dt = 0; dt < 4; ++dt) {
        *(f32x4*)&red[head][lane][dt * 4]      = acc0[dt];
        *(f32x4*)&red[head][lane][16 + dt * 4] = acc1[dt];
      }
      red[head][lane][32] = den0;
      red[head][lane][33] = den1;
    }
    __syncthreads();
    if (jseg == 0) {
      #pragma unroll
      for (int dt = 0; dt < 4; ++dt) {
        acc0[dt] += *(const f32x4*)&red[head][lane][dt * 4];
        acc1[dt] += *(const f32x4*)&red[head][lane][16 + dt * 4];
      }
      den0 += red[head][lane][32];
      den1 += red[head][lane][33];
    }
    __syncthreads();
  }
  if (jseg != 0) return;

  // normalize + store. C layout: col(lane&15)=d, row(kg*4+r)=i-within-group
  #pragma unroll
  for (int r = 0; r < 4; ++r) {
    float dr0 = __shfl(den0, kg * 4 + r, 64);
    float dr1 = __shfl(den1, kg * 4 + r, 64);
    float rc0 = 1.0f / dr0, rc1 = 1.0f / dr1;
    float* op0 = out + (size_t)(i0 + kg * 4 + r) * 256 + head * 64 + lo;
    float* op1 = out + (size_t)(i0 + 16 + kg * 4 + r) * 256 + head * 64 + lo;
    #pragma unroll
    for (int dt = 0; dt < 4; ++dt) {
      op0[dt * 16] = acc0[dt][r] * rc0;
      op1[dt * 16] = acc1[dt][r] * rc1;
    }
  }
}

extern "C" void kernel_launch(void* const* d_in, const int* in_sizes, int n_in,
                              void* d_out, int out_size, void* d_ws, size_t ws_size,
                              hipStream_t stream) {
  const float* h   = (const float*)d_in[0];
  const int*   adj = (const int*)d_in[1];
  const float* W   = (const float*)d_in[2];
  const float* a   = (const float*)d_in[3];
  float* out = (float*)d_out;
  float* s1 = (float*)d_ws;                                    // 4*8192 f32
  float* s2 = s1 + 4 * NND;                                    // 4*8192 f32
  unsigned short* whbT = (unsigned short*)(s2 + 4 * NND);      // 256*8192 bf16 = 4MB
  gat_phase1<<<dim3(NND / 16), dim3(256), 0, stream>>>(h, W, a, s1, s2, whbT);
  gat_phase2<<<dim3(NND / 32), dim3(1024), 0, stream>>>(adj, s1, s2, whbT, out);
}

// Round 4
// 564.399 us; speedup vs baseline: 1.1493x; 1.0063x over previous
//
#include <hip/hip_runtime.h>
#include <hip/hip_bf16.h>

#define NND 8192

typedef __attribute__((ext_vector_type(8))) __bf16 bf16x8;
typedef __attribute__((ext_vector_type(4))) float f32x4;
typedef __attribute__((ext_vector_type(4))) unsigned int u32x4;
typedef __attribute__((ext_vector_type(2))) unsigned int u32x2;

// ---------------- Phase 0: adj -> bitmask (268MB HBM stream, BW-bound) ----
__global__ __launch_bounds__(256) void gat_phase0(
    const int* __restrict__ adj, unsigned long long* __restrict__ bits)
{
  const int wave = threadIdx.x >> 6, lane = threadIdx.x & 63;
  const int row = blockIdx.x * 4 + wave;
  const int* ap = adj + (size_t)row * NND + lane;
  unsigned long long* bp = bits + (size_t)row * 128;
  #pragma unroll 4
  for (int it = 0; it < 128; ++it) {
    int v = ap[it * 64];
    unsigned long long m = __ballot(v != 0);
    if (lane == 0) bp[it] = m;
  }
}

// ---------------- Phase 1a: q1/q2[h][k] = log2e * sum_d W[h][k][d]*a[d] ----
__global__ __launch_bounds__(256) void gat_phase1a(
    const float* __restrict__ W, const float* __restrict__ av,
    float* __restrict__ q1, float* __restrict__ q2)
{
  const int t = blockIdx.x * 256 + threadIdx.x;   // 0..1023 = (head, k)
  const float* wp = W + (size_t)t * 64;
  float p1 = 0.f, p2 = 0.f;
  #pragma unroll
  for (int d = 0; d < 64; d += 4) {
    f32x4 w  = *(const f32x4*)(wp + d);
    f32x4 a1 = *(const f32x4*)(av + d);
    f32x4 a2 = *(const f32x4*)(av + 64 + d);
    p1 += w[0]*a1[0] + w[1]*a1[1] + w[2]*a1[2] + w[3]*a1[3];
    p2 += w[0]*a2[0] + w[1]*a2[1] + w[2]*a2[2] + w[3]*a2[3];
  }
  q1[t] = p1 * 1.4426950408889634f;
  q2[t] = p2 * 1.4426950408889634f;
}

// ---------------- Phase 1: Wh via MFMA -> whbF (phase-2 fragment order) ----
// wave=(head,dt). W-frags held in regs (loaded once). A=h rows (f32x4 loads).
// whbF chunk (head,dt,jtg,ks): 64 lanes x 16B; lane l=(kg2*16+lo2), elem e:
//   Wh[jtg*64 + kg2*16 + ks*8 + e][dt*16 + lo2]   (bf16)
__global__ __launch_bounds__(1024) void gat_phase1(
    const float* __restrict__ hin, const float* __restrict__ W,
    const float* __restrict__ q1, const float* __restrict__ q2,
    float* __restrict__ s1, float* __restrict__ s2, unsigned int* __restrict__ whbF)
{
  const int t = threadIdx.x;
  const int wave = t >> 6, lane = t & 63;
  const int head = wave & 3, dt = wave >> 2;
  const int lo = lane & 15, kg = lane >> 4;
  const float* Wp = W + head * 16384 + dt * 16 + lo;
  bf16x8 wf[8];                                     // one-time B-frags (W)
  #pragma unroll
  for (int ks = 0; ks < 8; ++ks)
    #pragma unroll
    for (int e = 0; e < 8; ++e)
      wf[ks][e] = (__bf16)Wp[(ks * 32 + kg * 8 + e) * 64];
  const float* q1h = q1 + head * 256;
  const float* q2h = q2 + head * 256;

  #pragma unroll
  for (int c = 0; c < 2; ++c) {
    const int n0 = blockIdx.x * 32 + c * 16;
    const float* hrow = hin + (size_t)(n0 + lo) * 256;
    f32x4 acc = (f32x4)(0.f);
    float p1 = 0.f, p2 = 0.f;
    #pragma unroll
    for (int ks = 0; ks < 8; ++ks) {
      const int kb = ks * 32 + kg * 8;
      f32x4 h0 = *(const f32x4*)(hrow + kb);
      f32x4 h1 = *(const f32x4*)(hrow + kb + 4);
      bf16x8 hf;
      #pragma unroll
      for (int e = 0; e < 4; ++e) { hf[e] = (__bf16)h0[e]; hf[e + 4] = (__bf16)h1[e]; }
      acc = __builtin_amdgcn_mfma_f32_16x16x32_bf16(hf, wf[ks], acc, 0, 0, 0);
      if (dt == 0) {
        f32x4 qa = *(const f32x4*)(q1h + kb);
        f32x4 qb = *(const f32x4*)(q1h + kb + 4);
        f32x4 qc = *(const f32x4*)(q2h + kb);
        f32x4 qd = *(const f32x4*)(q2h + kb + 4);
        #pragma unroll
        for (int e = 0; e < 4; ++e) {
          p1 = fmaf(h0[e], qa[e], p1); p1 = fmaf(h1[e], qb[e], p1);
          p2 = fmaf(h0[e], qc[e], p2); p2 = fmaf(h1[e], qd[e], p2);
        }
      }
    }
    // C: lane(kg,lo) reg r = Wh[n0+kg*4+r][dt*16+lo] -> frag slot:
    // kg2=sub=(n0>>4)&3, ks2=kg>>1, e2=(kg&1)*4+r, lo2=lo
    const int jtg = n0 >> 6, sub = (n0 >> 4) & 3;
    const int chunk = ((head * 4 + dt) * 128 + jtg) * 2 + (kg >> 1);
    unsigned short b0 = __builtin_bit_cast(unsigned short, (__bf16)acc[0]);
    unsigned short b1 = __builtin_bit_cast(unsigned short, (__bf16)acc[1]);
    unsigned short b2 = __builtin_bit_cast(unsigned short, (__bf16)acc[2]);
    unsigned short b3 = __builtin_bit_cast(unsigned short, (__bf16)acc[3]);
    u32x2 wv; wv[0] = (unsigned)b0 | ((unsigned)b1 << 16);
    wv[1] = (unsigned)b2 | ((unsigned)b3 << 16);
    *(u32x2*)(whbF + (size_t)chunk * 256 + (sub * 16 + lo) * 4 + (kg & 1) * 2) = wv;
    if (dt == 0) {
      p1 += __shfl_xor(p1, 16, 64); p1 += __shfl_xor(p1, 32, 64);
      p2 += __shfl_xor(p2, 16, 64); p2 += __shfl_xor(p2, 32, 64);
      if (kg == 0) { s1[head * NND + n0 + lo] = p1; s2[head * NND + n0 + lo] = p2; }
    }
  }
}

// ---------------- Phase 2: fused masked-exp attention + PV ----------------
// 16 waves = 4 heads x 4 jsegs; 32 rows/block; grid 256. Barrier-free loop.
// Denominator via 5th MFMA with B=ones (lands in C-layout per-row).
__global__ __launch_bounds__(1024) void gat_phase2(
    const unsigned long long* __restrict__ bits, const float* __restrict__ s1,
    const float* __restrict__ s2, const unsigned short* __restrict__ whbF,
    float* __restrict__ out)
{
  __shared__ float red[4][64][44];   // 44KB, epilogue-only (16B-aligned stride)
  const int t = threadIdx.x;
  const int wave = t >> 6, lane = t & 63;
  const int head = wave & 3, jseg = wave >> 2;
  const int i0 = blockIdx.x * 32;
  const int lo = lane & 15, kg = lane >> 4;
  const float s1v0 = s1[head * NND + i0 + lo];
  const float s1v1 = s1[head * NND + i0 + 16 + lo];
  const unsigned char* br0 = (const unsigned char*)bits + (size_t)(i0 + lo) * 1024 + kg * 2;
  const unsigned char* br1 = br0 + 16 * 1024;
  const float* s2h = s2 + head * NND;
  const char* wfb = (const char*)whbF + (size_t)head * 1048576 + (size_t)lane * 16;
  f32x4 acc0[4], acc1[4], dn0 = (f32x4)(0.f), dn1 = (f32x4)(0.f);
  #pragma unroll
  for (int dt = 0; dt < 4; ++dt) { acc0[dt] = (f32x4)(0.f); acc1[dt] = (f32x4)(0.f); }
  bf16x8 ones;
  #pragma unroll
  for (int e = 0; e < 8; ++e) ones[e] = (__bf16)1.0f;

  auto mkaf = [&](float s1v, unsigned m, f32x4 sa, f32x4 sb, int bb) -> bf16x8 {
    bf16x8 af;
    #pragma unroll
    for (int e = 0; e < 4; ++e) {
      float x = s1v + sa[e];
      x = fmaxf(x, 0.2f * x);
      float w = __builtin_amdgcn_exp2f(x);
      w = ((m >> (bb + e)) & 1u) ? w : 0.0f;
      af[e] = (__bf16)w;
    }
    #pragma unroll
    for (int e = 0; e < 4; ++e) {
      float x = s1v + sb[e];
      x = fmaxf(x, 0.2f * x);
      float w = __builtin_amdgcn_exp2f(x);
      w = ((m >> (bb + 4 + e)) & 1u) ? w : 0.0f;
      af[e + 4] = (__bf16)w;
    }
    return af;
  };

  #pragma unroll 2
  for (int jt = 0; jt < 32; ++jt) {
    const int jtg = jseg * 32 + jt;
    const int j0 = jtg * 64;
    u32x4 bb[8];
    #pragma unroll
    for (int dt = 0; dt < 4; ++dt)
      #pragma unroll
      for (int ks = 0; ks < 2; ++ks)
        bb[dt * 2 + ks] = *(const u32x4*)(wfb + dt * 262144 + jtg * 2048 + ks * 1024);
    const unsigned m0 = *(const unsigned short*)(br0 + (j0 >> 3));
    const unsigned m1 = *(const unsigned short*)(br1 + (j0 >> 3));
    const f32x4 sv0 = *(const f32x4*)(s2h + j0 + kg * 16);
    const f32x4 sv1 = *(const f32x4*)(s2h + j0 + kg * 16 + 4);
    const f32x4 sv2 = *(const f32x4*)(s2h + j0 + kg * 16 + 8);
    const f32x4 sv3 = *(const f32x4*)(s2h + j0 + kg * 16 + 12);
    {
      bf16x8 af = mkaf(s1v0, m0, sv0, sv1, 0);
      acc0[0] = __builtin_amdgcn_mfma_f32_16x16x32_bf16(af, __builtin_bit_cast(bf16x8, bb[0]), acc0[0], 0, 0, 0);
      acc0[1] = __builtin_amdgcn_mfma_f32_16x16x32_bf16(af, __builtin_bit_cast(bf16x8, bb[2]), acc0[1], 0, 0, 0);
      acc0[2] = __builtin_amdgcn_mfma_f32_16x16x32_bf16(af, __builtin_bit_cast(bf16x8, bb[4]), acc0[2], 0, 0, 0);
      acc0[3] = __builtin_amdgcn_mfma_f32_16x16x32_bf16(af, __builtin_bit_cast(bf16x8, bb[6]), acc0[3], 0, 0, 0);
      dn0 = __builtin_amdgcn_mfma_f32_16x16x32_bf16(af, ones, dn0, 0, 0, 0);
      af = mkaf(s1v0, m0, sv2, sv3, 8);
      acc0[0] = __builtin_amdgcn_mfma_f32_16x16x32_bf16(af, __builtin_bit_cast(bf16x8, bb[1]), acc0[0], 0, 0, 0);
      acc0[1] = __builtin_amdgcn_mfma_f32_16x16x32_bf16(af, __builtin_bit_cast(bf16x8, bb[3]), acc0[1], 0, 0, 0);
      acc0[2] = __builtin_amdgcn_mfma_f32_16x16x32_bf16(af, __builtin_bit_cast(bf16x8, bb[5]), acc0[2], 0, 0, 0);
      acc0[3] = __builtin_amdgcn_mfma_f32_16x16x32_bf16(af, __builtin_bit_cast(bf16x8, bb[7]), acc0[3], 0, 0, 0);
      dn0 = __builtin_amdgcn_mfma_f32_16x16x32_bf16(af, ones, dn0, 0, 0, 0);
    }
    {
      bf16x8 af = mkaf(s1v1, m1, sv0, sv1, 0);
      acc1[0] = __builtin_amdgcn_mfma_f32_16x16x32_bf16(af, __builtin_bit_cast(bf16x8, bb[0]), acc1[0], 0, 0, 0);
      acc1[1] = __builtin_amdgcn_mfma_f32_16x16x32_bf16(af, __builtin_bit_cast(bf16x8, bb[2]), acc1[1], 0, 0, 0);
      acc1[2] = __builtin_amdgcn_mfma_f32_16x16x32_bf16(af, __builtin_bit_cast(bf16x8, bb[4]), acc1[2], 0, 0, 0);
      acc1[3] = __builtin_amdgcn_mfma_f32_16x16x32_bf16(af, __builtin_bit_cast(bf16x8, bb[6]), acc1[3], 0, 0, 0);
      dn1 = __builtin_amdgcn_mfma_f32_16x16x32_bf16(af, ones, dn1, 0, 0, 0);
      af = mkaf(s1v1, m1, sv2, sv3, 8);
      acc1[0] = __builtin_amdgcn_mfma_f32_16x16x32_bf16(af, __builtin_bit_cast(bf16x8, bb[1]), acc1[0], 0, 0, 0);
      acc1[1] = __builtin_amdgcn_mfma_f32_16x16x32_bf16(af, __builtin_bit_cast(bf16x8, bb[3]), acc1[1], 0, 0, 0);
      acc1[2] = __builtin_amdgcn_mfma_f32_16x16x32_bf16(af, __builtin_bit_cast(bf16x8, bb[5]), acc1[2], 0, 0, 0);
      acc1[3] = __builtin_amdgcn_mfma_f32_16x16x32_bf16(af, __builtin_bit_cast(bf16x8, bb[7]), acc1[3], 0, 0, 0);
      dn1 = __builtin_amdgcn_mfma_f32_16x16x32_bf16(af, ones, dn1, 0, 0, 0);
    }
  }

  // cross-jseg reduction
  for (int s = 1; s <= 3; ++s) {
    if (jseg == s) {
      #pragma unroll
      for (int dt = 0; dt < 4; ++dt) {
        *(f32x4*)&red[head][lane][dt * 4] = acc0[dt];
        *(f32x4*)&red[head][lane][16 + dt * 4] = acc1[dt];
      }
      *(f32x4*)&red[head][lane][32] = dn0;
      *(f32x4*)&red[head][lane][36] = dn1;
    }
    __syncthreads();
    if (jseg == 0) {
      #pragma unroll
      for (int dt = 0; dt < 4; ++dt) {
        acc0[dt] += *(const f32x4*)&red[head][lane][dt * 4];
        acc1[dt] += *(const f32x4*)&red[head][lane][16 + dt * 4];
      }
      dn0 += *(const f32x4*)&red[head][lane][32];
      dn1 += *(const f32x4*)&red[head][lane][36];
    }
    __syncthreads();
  }
  if (jseg != 0) return;

  // normalize + store; den already per-row in C layout (no shuffles)
  #pragma unroll
  for (int r = 0; r < 4; ++r) {
    const float rc0 = 1.0f / dn0[r], rc1 = 1.0f / dn1[r];
    float* op0 = out + (size_t)(i0 + kg * 4 + r) * 256 + head * 64 + lo;
    float* op1 = op0 + 16 * 256;
    #pragma unroll
    for (int dt = 0; dt < 4; ++dt) {
      op0[dt * 16] = acc0[dt][r] * rc0;
      op1[dt * 16] = acc1[dt][r] * rc1;
    }
  }
}

extern "C" void kernel_launch(void* const* d_in, const int* in_sizes, int n_in,
                              void* d_out, int out_size, void* d_ws, size_t ws_size,
                              hipStream_t stream) {
  const float* h   = (const float*)d_in[0];
  const int*   adj = (const int*)d_in[1];
  const float* W   = (const float*)d_in[2];
  const float* a   = (const float*)d_in[3];
  float* out = (float*)d_out;
  float* s1 = (float*)d_ws;                       // 4*8192 f32   (128KB)
  float* s2 = s1 + 4 * NND;                       // 4*8192 f32   (128KB)
  float* q1 = s2 + 4 * NND;                       // 1024 f32     (4KB)
  float* q2 = q1 + 1024;                          // 1024 f32     (4KB)
  unsigned long long* bits = (unsigned long long*)(q2 + 1024);   // 8MB
  unsigned int* whbF = (unsigned int*)(bits + (size_t)NND * 128); // 4MB
  gat_phase0<<<dim3(NND / 4), dim3(256), 0, stream>>>(adj, bits);
  gat_phase1a<<<dim3(4), dim3(256), 0, stream>>>(W, a, q1, q2);
  gat_phase1<<<dim3(NND / 32), dim3(1024), 0, stream>>>(h, W, q1, q2, s1, s2, whbF);
  gat_phase2<<<dim3(NND / 32), dim3(1024), 0, stream>>>(bits, s1, s2, (const unsigned short*)whbF, out);
}

// Round 8
// 542.068 us; speedup vs baseline: 1.1966x; 1.0412x over previous
//
#include <hip/hip_runtime.h>
#include <hip/hip_bf16.h>

#define NND 8192

typedef __attribute__((ext_vector_type(8))) __bf16 bf16x8;
typedef __attribute__((ext_vector_type(4))) float f32x4;
typedef __attribute__((ext_vector_type(4))) unsigned int u32x4;
typedef __attribute__((ext_vector_type(2))) unsigned int u32x2;

// ---------------- Phase 0: adj -> bitmask (268MB HBM stream, BW-bound) ----
__global__ __launch_bounds__(256) void gat_phase0(
    const int* __restrict__ adj, unsigned long long* __restrict__ bits)
{
  const int wave = threadIdx.x >> 6, lane = threadIdx.x & 63;
  const int row = blockIdx.x * 4 + wave;
  const int* ap = adj + (size_t)row * NND + lane;
  unsigned long long* bp = bits + (size_t)row * 128;
  #pragma unroll 4
  for (int it = 0; it < 128; ++it) {
    int v = ap[it * 64];
    unsigned long long m = __ballot(v != 0);
    if (lane == 0) bp[it] = m;
  }
}

// ---------------- Phase 1a: q1/q2[h][k] = log2e * sum_d W[h][k][d]*a[d] ----
__global__ __launch_bounds__(256) void gat_phase1a(
    const float* __restrict__ W, const float* __restrict__ av,
    float* __restrict__ q1, float* __restrict__ q2)
{
  const int t = blockIdx.x * 256 + threadIdx.x;   // 0..1023 = (head, k)
  const float* wp = W + (size_t)t * 64;
  float p1 = 0.f, p2 = 0.f;
  #pragma unroll
  for (int d = 0; d < 64; d += 4) {
    f32x4 w  = *(const f32x4*)(wp + d);
    f32x4 a1 = *(const f32x4*)(av + d);
    f32x4 a2 = *(const f32x4*)(av + 64 + d);
    p1 += w[0]*a1[0] + w[1]*a1[1] + w[2]*a1[2] + w[3]*a1[3];
    p2 += w[0]*a2[0] + w[1]*a2[1] + w[2]*a2[2] + w[3]*a2[3];
  }
  q1[t] = p1 * 1.4426950408889634f;
  q2[t] = p2 * 1.4426950408889634f;
}

// ---------------- Phase 1: Wh via MFMA -> whbF (phase-2 fragment order) ----
// 4-wave blocks (wave=head), 16 rows/block, grid 512. h-fragments built once
// per wave, reused across all 4 d-tiles. Same whbF layout as verified before:
// chunk (head,dt,jtg,ks): lane l=(kg2*16+lo2), elem e:
//   Wh[jtg*64 + kg2*16 + ks*8 + e][dt*16 + lo2]   (bf16)
__global__ __launch_bounds__(256) void gat_phase1(
    const float* __restrict__ hin, const float* __restrict__ W,
    const float* __restrict__ q1, const float* __restrict__ q2,
    float* __restrict__ s1, float* __restrict__ s2, unsigned int* __restrict__ whbF)
{
  const int t = threadIdx.x;
  const int head = t >> 6, lane = t & 63;
  const int lo = lane & 15, kg = lane >> 4;
  const int n0 = blockIdx.x * 16;
  const float* hrow = hin + (size_t)(n0 + lo) * 256;
  const float* q1h = q1 + head * 256;
  const float* q2h = q2 + head * 256;
  bf16x8 hf[8];
  float p1 = 0.f, p2 = 0.f;
  #pragma unroll
  for (int ks = 0; ks < 8; ++ks) {
    const int kb = ks * 32 + kg * 8;
    f32x4 h0 = *(const f32x4*)(hrow + kb);
    f32x4 h1 = *(const f32x4*)(hrow + kb + 4);
    #pragma unroll
    for (int e = 0; e < 4; ++e) { hf[ks][e] = (__bf16)h0[e]; hf[ks][e + 4] = (__bf16)h1[e]; }
    f32x4 qa = *(const f32x4*)(q1h + kb);
    f32x4 qb = *(const f32x4*)(q1h + kb + 4);
    f32x4 qc = *(const f32x4*)(q2h + kb);
    f32x4 qd = *(const f32x4*)(q2h + kb + 4);
    #pragma unroll
    for (int e = 0; e < 4; ++e) {
      p1 = fmaf(h0[e], qa[e], p1); p1 = fmaf(h1[e], qb[e], p1);
      p2 = fmaf(h0[e], qc[e], p2); p2 = fmaf(h1[e], qd[e], p2);
    }
  }
  p1 += __shfl_xor(p1, 16, 64); p1 += __shfl_xor(p1, 32, 64);
  p2 += __shfl_xor(p2, 16, 64); p2 += __shfl_xor(p2, 32, 64);
  if (kg == 0) { s1[head * NND + n0 + lo] = p1; s2[head * NND + n0 + lo] = p2; }

  const int jtg = n0 >> 6, sub = (n0 >> 4) & 3;
  #pragma unroll
  for (int dt = 0; dt < 4; ++dt) {
    const float* Wp = W + head * 16384 + dt * 16 + lo;
    f32x4 acc = (f32x4)(0.f);
    #pragma unroll
    for (int ks = 0; ks < 8; ++ks) {
      const int kb = ks * 32 + kg * 8;
      bf16x8 wf;
      #pragma unroll
      for (int e = 0; e < 8; ++e)
        wf[e] = (__bf16)Wp[(kb + e) * 64];
      acc = __builtin_amdgcn_mfma_f32_16x16x32_bf16(hf[ks], wf, acc, 0, 0, 0);
    }
    const int chunk = ((head * 4 + dt) * 128 + jtg) * 2 + (kg >> 1);
    unsigned short b0 = __builtin_bit_cast(unsigned short, (__bf16)acc[0]);
    unsigned short b1 = __builtin_bit_cast(unsigned short, (__bf16)acc[1]);
    unsigned short b2 = __builtin_bit_cast(unsigned short, (__bf16)acc[2]);
    unsigned short b3 = __builtin_bit_cast(unsigned short, (__bf16)acc[3]);
    u32x2 wv; wv[0] = (unsigned)b0 | ((unsigned)b1 << 16);
    wv[1] = (unsigned)b2 | ((unsigned)b3 << 16);
    *(u32x2*)(whbF + (size_t)chunk * 256 + (sub * 16 + lo) * 4 + (kg & 1) * 2) = wv;
  }
}

// ---------------- Phase 2: fused masked-exp attention + PV ----------------
// 8 waves = 4 heads x 2 rowgroups; 32 rows/block; grid 256. Each wave sweeps
// the FULL j range: no barriers, no LDS, denominator completes per-wave via
// ones-MFMA. Double-buffered register prefetch (bb/sv/mask) hides L2 latency.
__global__ __launch_bounds__(512) void gat_phase2(
    const unsigned long long* __restrict__ bits, const float* __restrict__ s1,
    const float* __restrict__ s2, const unsigned short* __restrict__ whbF,
    float* __restrict__ out)
{
  const int t = threadIdx.x;
  const int wave = t >> 6, lane = t & 63;
  const int head = wave & 3, rg = wave >> 2;
  const int i0 = blockIdx.x * 32 + rg * 16;
  const int lo = lane & 15, kg = lane >> 4;
  const float s1v = s1[head * NND + i0 + lo];
  const unsigned char* br = (const unsigned char*)bits + (size_t)(i0 + lo) * 1024 + kg * 2;
  const float* s2h = s2 + head * NND;
  const char* wfb = (const char*)whbF + (size_t)head * 1048576 + (size_t)lane * 16;
  f32x4 acc[4], dn = (f32x4)(0.f);
  #pragma unroll
  for (int dt = 0; dt < 4; ++dt) acc[dt] = (f32x4)(0.f);
  bf16x8 ones;
  #pragma unroll
  for (int e = 0; e < 8; ++e) ones[e] = (__bf16)1.0f;

  auto mkaf = [&](unsigned m, f32x4 sa, f32x4 sb, int bb) -> bf16x8 {
    bf16x8 af;
    #pragma unroll
    for (int e = 0; e < 4; ++e) {
      float x = s1v + sa[e];
      x = fmaxf(x, 0.2f * x);
      float w = __builtin_amdgcn_exp2f(x);
      w = ((m >> (bb + e)) & 1u) ? w : 0.0f;
      af[e] = (__bf16)w;
    }
    #pragma unroll
    for (int e = 0; e < 4; ++e) {
      float x = s1v + sb[e];
      x = fmaxf(x, 0.2f * x);
      float w = __builtin_amdgcn_exp2f(x);
      w = ((m >> (bb + 4 + e)) & 1u) ? w : 0.0f;
      af[e + 4] = (__bf16)w;
    }
    return af;
  };

  auto LOADT = [&](u32x4 (&bb)[8], f32x4 (&sv)[4], unsigned& m, int jtg) {
    #pragma unroll
    for (int dt = 0; dt < 4; ++dt)
      #pragma unroll
      for (int ks = 0; ks < 2; ++ks)
        bb[dt * 2 + ks] = *(const u32x4*)(wfb + dt * 262144 + jtg * 2048 + ks * 1024);
    m = *(const unsigned short*)(br + jtg * 8);
    const int j0 = jtg * 64;
    sv[0] = *(const f32x4*)(s2h + j0 + kg * 16);
    sv[1] = *(const f32x4*)(s2h + j0 + kg * 16 + 4);
    sv[2] = *(const f32x4*)(s2h + j0 + kg * 16 + 8);
    sv[3] = *(const f32x4*)(s2h + j0 + kg * 16 + 12);
  };

  auto COMP = [&](u32x4 (&bb)[8], f32x4 (&sv)[4], unsigned m) {
    bf16x8 af = mkaf(m, sv[0], sv[1], 0);
    acc[0] = __builtin_amdgcn_mfma_f32_16x16x32_bf16(af, __builtin_bit_cast(bf16x8, bb[0]), acc[0], 0, 0, 0);
    acc[1] = __builtin_amdgcn_mfma_f32_16x16x32_bf16(af, __builtin_bit_cast(bf16x8, bb[2]), acc[1], 0, 0, 0);
    acc[2] = __builtin_amdgcn_mfma_f32_16x16x32_bf16(af, __builtin_bit_cast(bf16x8, bb[4]), acc[2], 0, 0, 0);
    acc[3] = __builtin_amdgcn_mfma_f32_16x16x32_bf16(af, __builtin_bit_cast(bf16x8, bb[6]), acc[3], 0, 0, 0);
    dn = __builtin_amdgcn_mfma_f32_16x16x32_bf16(af, ones, dn, 0, 0, 0);
    af = mkaf(m, sv[2], sv[3], 8);
    acc[0] = __builtin_amdgcn_mfma_f32_16x16x32_bf16(af, __builtin_bit_cast(bf16x8, bb[1]), acc[0], 0, 0, 0);
    acc[1] = __builtin_amdgcn_mfma_f32_16x16x32_bf16(af, __builtin_bit_cast(bf16x8, bb[3]), acc[1], 0, 0, 0);
    acc[2] = __builtin_amdgcn_mfma_f32_16x16x32_bf16(af, __builtin_bit_cast(bf16x8, bb[5]), acc[2], 0, 0, 0);
    acc[3] = __builtin_amdgcn_mfma_f32_16x16x32_bf16(af, __builtin_bit_cast(bf16x8, bb[7]), acc[3], 0, 0, 0);
    dn = __builtin_amdgcn_mfma_f32_16x16x32_bf16(af, ones, dn, 0, 0, 0);
  };

  u32x4 bbA[8], bbB[8];
  f32x4 svA[4], svB[4];
  unsigned mA, mB;

  LOADT(bbA, svA, mA, 0);
  for (int p = 0; p < 63; ++p) {
    LOADT(bbB, svB, mB, 2 * p + 1);
    COMP(bbA, svA, mA);
    LOADT(bbA, svA, mA, 2 * p + 2);
    COMP(bbB, svB, mB);
  }
  LOADT(bbB, svB, mB, 127);
  COMP(bbA, svA, mA);
  COMP(bbB, svB, mB);

  // normalize + store; dn already per-row in C layout (no shuffles needed)
  #pragma unroll
  for (int r = 0; r < 4; ++r) {
    const float rc = 1.0f / dn[r];
    float* op = out + (size_t)(i0 + kg * 4 + r) * 256 + head * 64 + lo;
    #pragma unroll
    for (int dt = 0; dt < 4; ++dt)
      op[dt * 16] = acc[dt][r] * rc;
  }
}

extern "C" void kernel_launch(void* const* d_in, const int* in_sizes, int n_in,
                              void* d_out, int out_size, void* d_ws, size_t ws_size,
                              hipStream_t stream) {
  const float* h   = (const float*)d_in[0];
  const int*   adj = (const int*)d_in[1];
  const float* W   = (const float*)d_in[2];
  const float* a   = (const float*)d_in[3];
  float* out = (float*)d_out;
  float* s1 = (float*)d_ws;                       // 4*8192 f32   (128KB)
  float* s2 = s1 + 4 * NND;                       // 4*8192 f32   (128KB)
  float* q1 = s2 + 4 * NND;                       // 1024 f32     (4KB)
  float* q2 = q1 + 1024;                          // 1024 f32     (4KB)
  unsigned long long* bits = (unsigned long long*)(q2 + 1024);    // 8MB
  unsigned int* whbF = (unsigned int*)(bits + (size_t)NND * 128); // 4MB
  gat_phase0<<<dim3(NND / 4), dim3(256), 0, stream>>>(adj, bits);
  gat_phase1a<<<dim3(4), dim3(256), 0, stream>>>(W, a, q1, q2);
  gat_phase1<<<dim3(NND / 16), dim3(256), 0, stream>>>(h, W, q1, q2, s1, s2, whbF);
  gat_phase2<<<dim3(NND / 32), dim3(512), 0, stream>>>(bits, s1, s2, (const unsigned short*)whbF, out);
}